// Round 1
// baseline (784.654 us; speedup 1.0000x reference)
//
#include <hip/hip_runtime.h>

#define N_NODES 100000
#define N_EDGES 1600000
#define NBUCK 250          // buckets per (layer,rel)
#define BSZ 400            // nodes per bucket (250*400 = 100000)
#define CHUNK 8192         // edges per partition block
#define NCHUNK 196         // ceil(E/CHUNK)
#define CAP 8192           // LDS staging capacity in k_bsort
#define MTILES 6250        // N_NODES / 16
#define NTILE 13           // src tiles of 8192 rows (100000 >> 13 -> 0..12)
#define NKEY (BSZ * NTILE) // 5200 sort bins
#define NKEYP 5376         // padded to 21*256

typedef _Float16 half8 __attribute__((ext_vector_type(8)));
typedef _Float16 half4v __attribute__((ext_vector_type(4)));
typedef _Float16 half2v __attribute__((ext_vector_type(2)));
typedef float floatx4 __attribute__((ext_vector_type(4)));

// workspace layout (bytes), total ~191.4 MB:
#define OFF_DEG   0ull           // 12N int: per layer, out r0..2 then in r0..2
#define OFF_GC    4800000ull     // 1500 int (pad 6144) dst-bucket counts
#define OFF_BB    4806144ull     // dst bucket bases
#define OFF_BC    4812288ull     // dst bucket cursors
#define OFF_RS    4818432ull     // 12N float
#define OFF_START 9618432ull     // 6N int
#define OFF_PAIRS 12018432ull    // 6E int
#define OFF_XH    50418432ull    // N*128 fp16 (row-major)
#define OFF_W1F   76018432ull    // 96*512 fp16 (frag order)
#define OFF_W2F   76116736ull    // 48*512 fp16 (frag order)
#define OFF_AGG   76165888ull    // N*384 fp16, A-frag layout; head reused as src-count scratch
#define OFF_HW    152965888ull   // N*192 fp16, row-major (pre-scaled by rs_out layer1)

// src-counting scratch aliased into agg region (dead until k_pull1):
#define OFF_DDS   OFF_AGG                    // 6E short = 19.2 MB
#define OFF_GCS   (OFF_AGG + 19200000ull)    // 1500 int (pad 6144)
#define OFF_BBS   (OFF_AGG + 19206144ull)    // 1500 int
#define OFF_BCS   (OFF_AGG + 19212288ull)    // 1500 int

__device__ __forceinline__ void lds_scan256(int* a) {
    int t = threadIdx.x;
    for (int off = 1; off < 256; off <<= 1) {
        int v = (t >= off) ? a[t - off] : 0;
        __syncthreads();
        a[t] += v;
        __syncthreads();
    }
}

// ---------------- fused bucket histograms of src AND dst ----------------
__global__ __launch_bounds__(256) void k_bhist2(const int* __restrict__ ei,
                                                int* __restrict__ gcount_d,
                                                int* __restrict__ gcount_s) {
    int lr = blockIdx.y;
    int e0 = blockIdx.x * CHUNK;
    int n = min(CHUNK, N_EDGES - e0);
    const int* bs = ei + (size_t)lr * 2 * N_EDGES + e0;
    const int* bd = bs + N_EDGES;
    __shared__ int lhs[256];
    __shared__ int lhd[256];
    int t = threadIdx.x;
    lhs[t] = 0; lhd[t] = 0;
    __syncthreads();
    for (int i = t; i < n; i += 256) {
        atomicAdd(&lhs[bs[i] / BSZ], 1);
        atomicAdd(&lhd[bd[i] / BSZ], 1);
    }
    __syncthreads();
    if (t < NBUCK) {
        if (lhd[t]) atomicAdd(&gcount_d[lr * NBUCK + t], lhd[t]);
        if (lhs[t]) atomicAdd(&gcount_s[lr * NBUCK + t], lhs[t]);
    }
}

// ---------------- scan bucket counts ----------------
__global__ __launch_bounds__(256) void k_bscan(const int* __restrict__ gcount,
                                               int* __restrict__ bbase,
                                               int* __restrict__ bcursor) {
    int lr = blockIdx.x, t = threadIdx.x;
    __shared__ int a[256];
    int v = (t < NBUCK) ? gcount[lr * NBUCK + t] : 0;
    a[t] = v;
    __syncthreads();
    lds_scan256(a);
    if (t < NBUCK) {
        int excl = a[t] - v;
        bbase[lr * NBUCK + t] = excl;
        bcursor[lr * NBUCK + t] = excl;
    }
}

// ---------------- partition edges into dst buckets (payload src|dd<<17) ----------------
__global__ __launch_bounds__(256) void k_bpart(const int* __restrict__ ei,
                                               int* __restrict__ bcursor,
                                               int* __restrict__ pairs) {
    int lr = blockIdx.y;
    int e0 = blockIdx.x * CHUNK;
    int n = min(CHUNK, N_EDGES - e0);
    const int* bs = ei + (size_t)lr * 2 * N_EDGES + e0;
    const int* bd = bs + N_EDGES;
    __shared__ int lh[256];
    __shared__ int lexcl[256];
    __shared__ int lcur[256];
    __shared__ int gb[256];
    __shared__ int staged[CHUNK];
    __shared__ unsigned char stb[CHUNK];
    int t = threadIdx.x;
    lh[t] = 0;
    __syncthreads();
    for (int i = t; i < n; i += 256)
        atomicAdd(&lh[bd[i] / BSZ], 1);
    __syncthreads();
    int cnt_t = lh[t];
    __syncthreads();
    lds_scan256(lh);
    int excl_t = lh[t] - cnt_t;
    lexcl[t] = excl_t;
    lcur[t] = excl_t;
    if (t < NBUCK) gb[t] = cnt_t ? atomicAdd(&bcursor[lr * NBUCK + t], cnt_t) : 0;
    __syncthreads();
    for (int i = t; i < n; i += 256) {
        int s = bs[i], d = bd[i];
        int b = d / BSZ;
        int dd = d - b * BSZ;
        int p = atomicAdd(&lcur[b], 1);
        staged[p] = s | (dd << 17);
        stb[p] = (unsigned char)b;
    }
    __syncthreads();
    int* outp = pairs + (size_t)lr * N_EDGES;
    for (int i = t; i < n; i += 256) {
        int b = stb[i];
        outp[gb[b] + (i - lexcl[b])] = staged[i];
    }
}

// ---------------- partition src into buckets (payload = 9-bit in-bucket offset) ----------------
__global__ __launch_bounds__(256) void k_bpart_s(const int* __restrict__ ei,
                                                 int* __restrict__ bcursor_s,
                                                 short* __restrict__ dds) {
    int lr = blockIdx.y;
    int e0 = blockIdx.x * CHUNK;
    int n = min(CHUNK, N_EDGES - e0);
    const int* bs = ei + (size_t)lr * 2 * N_EDGES + e0;
    __shared__ int lh[256];
    __shared__ int lexcl[256];
    __shared__ int lcur[256];
    __shared__ int gb[256];
    __shared__ short staged[CHUNK];
    __shared__ unsigned char stb[CHUNK];
    int t = threadIdx.x;
    lh[t] = 0;
    __syncthreads();
    for (int i = t; i < n; i += 256)
        atomicAdd(&lh[bs[i] / BSZ], 1);
    __syncthreads();
    int cnt_t = lh[t];
    __syncthreads();
    lds_scan256(lh);
    int excl_t = lh[t] - cnt_t;
    lexcl[t] = excl_t;
    lcur[t] = excl_t;
    if (t < NBUCK) gb[t] = cnt_t ? atomicAdd(&bcursor_s[lr * NBUCK + t], cnt_t) : 0;
    __syncthreads();
    for (int i = t; i < n; i += 256) {
        int s = bs[i];
        int b = s / BSZ;
        int p = atomicAdd(&lcur[b], 1);
        staged[p] = (short)(s - b * BSZ);
        stb[p] = (unsigned char)b;
    }
    __syncthreads();
    short* outp = dds + (size_t)lr * N_EDGES;
    for (int i = t; i < n; i += 256) {
        int b = stb[i];
        outp[gb[b] + (i - lexcl[b])] = staged[i];
    }
}

// ---------------- per-bucket src count -> out-degree (coalesced, no global atomics) ----------------
__global__ __launch_bounds__(256) void k_bcount_s(const int* __restrict__ bbase_s,
                                                  const short* __restrict__ dds,
                                                  int* __restrict__ deg) {
    int lr = blockIdx.y, b = blockIdx.x;
    int layer = lr / 3, r = lr % 3;
    int base = bbase_s[lr * NBUCK + b];
    int next = (b < NBUCK - 1) ? bbase_s[lr * NBUCK + b + 1] : N_EDGES;
    int cnt = next - base;
    const short* reg = dds + (size_t)lr * N_EDGES + base;
    __shared__ int h[BSZ];
    int t = threadIdx.x;
    h[t] = 0;
    if (t < BSZ - 256) h[t + 256] = 0;
    __syncthreads();
    for (int i = t; i < cnt; i += 256)
        atomicAdd(&h[reg[i]], 1);
    __syncthreads();
    int* degout = deg + (size_t)layer * 6 * N_NODES + (size_t)r * N_NODES + b * BSZ;
    degout[t] = h[t];
    if (t < BSZ - 256) degout[t + 256] = h[t + 256];
}

// ---------------- per-bucket counting sort by (dd, src-tile) + CSR + in-degree ----------------
__global__ __launch_bounds__(256) void k_bsort(const int* __restrict__ bbase,
                                               int* __restrict__ pairs,
                                               int* __restrict__ start,
                                               int* __restrict__ deg) {
    int lr = blockIdx.y, b = blockIdx.x;
    int layer = lr / 3, r = lr % 3;
    int base = bbase[lr * NBUCK + b];
    int next = (b < NBUCK - 1) ? bbase[lr * NBUCK + b + 1] : N_EDGES;
    int cnt = next - base;
    int* reg = pairs + (size_t)lr * N_EDGES + base;
    __shared__ int staged[CAP];      // 32 KB
    __shared__ int hist[NKEYP];      // 21.5 KB: counts -> exclusive starts -> cursors
    __shared__ int tsum[256];
    int t = threadIdx.x;
    for (int i = t; i < NKEYP; i += 256) hist[i] = 0;
    __syncthreads();
    for (int i = t; i < cnt; i += 256) {
        int v = reg[i];
        if (i < CAP) staged[i] = v;
        int key = (v >> 17) * NTILE + ((v & 0x1FFFF) >> 13);
        atomicAdd(&hist[key], 1);
    }
    __syncthreads();
    // scan 5376 bins: thread t owns bins [t*21, t*21+21)
    int b0 = t * 21;
    int loc[21];
    int s = 0;
#pragma unroll
    for (int k = 0; k < 21; k++) { loc[k] = s; s += hist[b0 + k]; }
    tsum[t] = s;
    __syncthreads();
    lds_scan256(tsum);               // inclusive
    int tbase = tsum[t] - s;
#pragma unroll
    for (int k = 0; k < 21; k++) hist[b0 + k] = tbase + loc[k];
    __syncthreads();
    // CSR start + in-degree from bin boundaries (hist[5200] == cnt via zero pad)
    int d0 = b * BSZ;
    {
        int st = hist[t * NTILE];
        int en = hist[(t + 1) * NTILE];
        start[(size_t)lr * N_NODES + d0 + t] = base + st;
        deg[(size_t)layer * 6 * N_NODES + (size_t)(3 + r) * N_NODES + d0 + t] = en - st;
        if (t < BSZ - 256) {
            int t2 = t + 256;
            int st2 = hist[t2 * NTILE];
            int en2 = hist[(t2 + 1) * NTILE];
            start[(size_t)lr * N_NODES + d0 + t2] = base + st2;
            deg[(size_t)layer * 6 * N_NODES + (size_t)(3 + r) * N_NODES + d0 + t2] = en2 - st2;
        }
    }
    __syncthreads();
    // scatter (hist becomes cursors)
    for (int i = t; i < cnt; i += 256) {
        int v = (i < CAP) ? staged[i] : reg[i];
        int key = (v >> 17) * NTILE + ((v & 0x1FFFF) >> 13);
        int p = atomicAdd(&hist[key], 1);
        reg[p] = v & 0x1FFFF;
    }
}

__global__ __launch_bounds__(256) void k_rsqrt(const int* __restrict__ deg,
                                               float* __restrict__ rs) {
    int i = blockIdx.x * 256 + threadIdx.x;
    if (i >= 12 * N_NODES) return;
    int v = deg[i];
    rs[i] = rsqrtf((float)(v < 1 ? 1 : v));
}

// ---------------- x -> fp16 ----------------
__global__ __launch_bounds__(256) void k_cvt_x(const float* __restrict__ x,
                                               _Float16* __restrict__ xh) {
    int i = blockIdx.x * 256 + threadIdx.x;
    if (i >= N_NODES * 64) return;
    float2 v = ((const float2*)x)[i];
    half2v h; h.x = (_Float16)v.x; h.y = (_Float16)v.y;
    ((half2v*)xh)[i] = h;
}

// ---------------- W1/W2 -> fp16 fragment order ----------------
__global__ __launch_bounds__(256) void k_repack(const float* __restrict__ W1,
                                                const float* __restrict__ W2,
                                                _Float16* __restrict__ W1f,
                                                _Float16* __restrict__ W2f) {
    int i = blockIdx.x * 256 + threadIdx.x;
    if (i < 96 * 512) {
        int g = i >> 9, rem = i & 511, L = rem >> 3, j = rem & 7;
        int kc = g >> 3, nt = g & 7;
        int k = kc * 32 + (L >> 4) * 8 + j;
        int n = nt * 16 + (L & 15);
        W1f[i] = (_Float16)W1[k * 128 + n];
    } else if (i < 96 * 512 + 48 * 512) {
        int ii = i - 96 * 512;
        int g = ii >> 9, rem = ii & 511, L = rem >> 3, j = rem & 7;
        int kc = g / 12, nt = g % 12;
        int k = kc * 32 + (L >> 4) * 8 + j;
        int n = nt * 16 + (L & 15);
        int r = n >> 6, c = n & 63;
        W2f[ii] = (_Float16)W2[r * 8192 + k * 64 + c];
    }
}

// ---------------- layer-1 per-relation gather: 2 edges per load instruction ----------------
// lanes 0-31 own edge q+0, lanes 32-63 own edge q+1; each lane loads half4 (8B)
// so one instruction fetches two full 256B x-rows -> 2x lines in flight, ~half the
// shfl/cvt/fma overhead per edge.
__device__ __forceinline__ void accum_rel1(const int* __restrict__ sorted, int j, int n,
                                           const float* __restrict__ rsrow,
                                           const half4v* __restrict__ x4,
                                           int lane, int half_id, int fl, float4& acc) {
    for (int base = 0; base < n; base += 64) {
        int c = n - base; if (c > 64) c = 64;
        int s_l = (lane < c) ? sorted[j + base + lane] : 0;
        float w_l = (lane < c) ? rsrow[s_l] : 0.f;
        int q = 0;
        for (; q + 16 <= c; q += 16) {
            int ss[8]; float ww[8]; half4v vv[8];
#pragma unroll
            for (int u = 0; u < 8; u++) {
                ss[u] = __shfl(s_l, q + 2 * u + half_id);
                ww[u] = __shfl(w_l, q + 2 * u + half_id);
            }
#pragma unroll
            for (int u = 0; u < 8; u++) vv[u] = x4[(size_t)ss[u] * 32 + fl];
#pragma unroll
            for (int u = 0; u < 8; u++) {
                acc.x += ww[u] * (float)vv[u][0];
                acc.y += ww[u] * (float)vv[u][1];
                acc.z += ww[u] * (float)vv[u][2];
                acc.w += ww[u] * (float)vv[u][3];
            }
        }
        for (; q + 2 <= c; q += 2) {
            int s = __shfl(s_l, q + half_id);
            float w = __shfl(w_l, q + half_id);
            half4v v = x4[(size_t)s * 32 + fl];
            acc.x += w * (float)v[0];
            acc.y += w * (float)v[1];
            acc.z += w * (float)v[2];
            acc.w += w * (float)v[3];
        }
        if (q < c) {               // single leftover edge: upper half contributes 0
            int s = __shfl(s_l, q);
            float w = __shfl(w_l, q);
            if (half_id) w = 0.f;
            half4v v = x4[(size_t)s * 32 + fl];
            acc.x += w * (float)v[0];
            acc.y += w * (float)v[1];
            acc.z += w * (float)v[2];
            acc.w += w * (float)v[3];
        }
    }
}

// ---------------- layer-1 pull ----------------
__global__ __launch_bounds__(256) void k_pull1(const int* __restrict__ sorted,
                                               const int* __restrict__ start,
                                               const int* __restrict__ deg,
                                               const float* __restrict__ rs,
                                               const _Float16* __restrict__ xh,
                                               _Float16* __restrict__ agg) {
    int wid = threadIdx.x >> 6, lane = threadIdx.x & 63;
    int dst = blockIdx.x * 4 + wid;
    if (dst >= N_NODES) return;
    int half_id = lane >> 5, fl = lane & 31;   // lane owns features 4*fl..4*fl+3
    const half4v* x4 = (const half4v*)xh;
    const int* deg0in = deg + 3 * N_NODES;
    float4 a0 = make_float4(0.f, 0.f, 0.f, 0.f), a1 = a0, a2 = a0;
    accum_rel1(sorted, start[dst], deg0in[dst], rs, x4, lane, half_id, fl, a0);
    accum_rel1(sorted + N_EDGES, start[N_NODES + dst], deg0in[N_NODES + dst],
               rs + N_NODES, x4, lane, half_id, fl, a1);
    accum_rel1(sorted + 2 * N_EDGES, start[2 * N_NODES + dst], deg0in[2 * N_NODES + dst],
               rs + 2 * N_NODES, x4, lane, half_id, fl, a2);
    size_t mbase = (size_t)(dst >> 4) * 48 * 128;
    int moff = (dst & 15) * 8;
#pragma unroll
    for (int r = 0; r < 3; r++) {
        float4 a = (r == 0) ? a0 : (r == 1) ? a1 : a2;
        // merge edge-parity halves (all lanes execute the shfls)
        a.x += __shfl_xor(a.x, 32);
        a.y += __shfl_xor(a.y, 32);
        a.z += __shfl_xor(a.z, 32);
        a.w += __shfl_xor(a.w, 32);
        if (half_id == (r & 1)) {  // spread the 3 stores across the two halves
            float w = rs[(size_t)(3 + r) * N_NODES + dst];
            int k = r * 128 + 4 * fl;
            size_t idx = mbase + (size_t)(k >> 3) * 128 + moff + (k & 7);
            half4v h;
            h[0] = (_Float16)(a.x * w);
            h[1] = (_Float16)(a.y * w);
            h[2] = (_Float16)(a.z * w);
            h[3] = (_Float16)(a.w * w);
            *(half4v*)(agg + idx) = h;
        }
    }
}

// ---------------- fused MFMA GEMM + rs_out(layer1) fold into hW ----------------
__global__ __launch_bounds__(256) void k_gemm12(const _Float16* __restrict__ Af,
                                                const _Float16* __restrict__ W1f,
                                                const float* __restrict__ b1,
                                                const _Float16* __restrict__ W2f,
                                                const float* __restrict__ rs1out,
                                                _Float16* __restrict__ hW) {
    __shared__ _Float16 Hs[4][2048];
    int tid = threadIdx.x;
    int w = tid >> 6, L = tid & 63;
    int mt = blockIdx.x * 4 + w;
    if (mt >= MTILES) return;
    const half8* A8 = (const half8*)Af;
    const half8* B1 = (const half8*)W1f;
    const half8* B2 = (const half8*)W2f;

    floatx4 acc[8];
#pragma unroll
    for (int nt = 0; nt < 8; nt++) acc[nt] = (floatx4)(0.f);
#pragma unroll
    for (int kc = 0; kc < 12; kc++) {
        half8 a = A8[(size_t)mt * 768 + kc * 64 + L];
#pragma unroll
        for (int nt = 0; nt < 8; nt++) {
            half8 b = B1[(kc * 8 + nt) * 64 + L];
            acc[nt] = __builtin_amdgcn_mfma_f32_16x16x32_f16(a, b, acc[nt], 0, 0, 0);
        }
    }
    int cl = L & 15, rw = L >> 4;
#pragma unroll
    for (int nt = 0; nt < 8; nt++) {
        int n = nt * 16 + cl;
        float bs = b1[n] + b1[128 + n] + b1[256 + n];
#pragma unroll
        for (int j = 0; j < 4; j++) {
            int mm = rw * 4 + j;
            float v = acc[nt][j] + bs;
            v = v > 0.f ? v : 0.f;
            Hs[w][(n >> 3) * 128 + mm * 8 + (n & 7)] = (_Float16)v;
        }
    }
    __syncthreads();

    const half8* H8 = (const half8*)(&Hs[w][0]);
    floatx4 acc2[12];
#pragma unroll
    for (int nt = 0; nt < 12; nt++) acc2[nt] = (floatx4)(0.f);
#pragma unroll
    for (int kc = 0; kc < 4; kc++) {
        half8 a = H8[kc * 64 + L];
#pragma unroll
        for (int nt = 0; nt < 12; nt++) {
            half8 b = B2[(kc * 12 + nt) * 64 + L];
            acc2[nt] = __builtin_amdgcn_mfma_f32_16x16x32_f16(a, b, acc2[nt], 0, 0, 0);
        }
    }
#pragma unroll
    for (int j = 0; j < 4; j++) {
        int mm = mt * 16 + rw * 4 + j;
        float wr[3] = {rs1out[mm], rs1out[N_NODES + mm], rs1out[2 * N_NODES + mm]};
#pragma unroll
        for (int nt = 0; nt < 12; nt++) {
            int n = nt * 16 + cl;
            hW[(size_t)mm * 192 + n] = (_Float16)(acc2[nt][j] * wr[nt >> 2]);
        }
    }
}

// ---------------- layer-2 per-relation gather: 2 edges per load (4B/lane half2) ----------------
// h2 already includes the relation offset (32*r half2 elements).
__device__ __forceinline__ void accum_rel2(const int* __restrict__ sorted, int j, int n,
                                           const half2v* __restrict__ h2,
                                           int lane, int half_id, int fl, float2& acc) {
    for (int base = 0; base < n; base += 64) {
        int c = n - base; if (c > 64) c = 64;
        int s_l = (lane < c) ? sorted[j + base + lane] : 0;
        int q = 0;
        for (; q + 16 <= c; q += 16) {
            int ss[8]; half2v vv[8];
#pragma unroll
            for (int u = 0; u < 8; u++) ss[u] = __shfl(s_l, q + 2 * u + half_id);
#pragma unroll
            for (int u = 0; u < 8; u++) vv[u] = h2[(size_t)ss[u] * 96 + fl];
#pragma unroll
            for (int u = 0; u < 8; u++) { acc.x += (float)vv[u].x; acc.y += (float)vv[u].y; }
        }
        for (; q + 2 <= c; q += 2) {
            int s = __shfl(s_l, q + half_id);
            half2v v = h2[(size_t)s * 96 + fl];
            acc.x += (float)v.x; acc.y += (float)v.y;
        }
        if (q < c) {               // single leftover edge: only lower half accumulates
            int s = __shfl(s_l, q);
            half2v v = h2[(size_t)s * 96 + fl];
            if (!half_id) { acc.x += (float)v.x; acc.y += (float)v.y; }
        }
    }
}

// ---------------- layer-2 pull ----------------
__global__ __launch_bounds__(256) void k_pull2(const int* __restrict__ sorted1,
                                               const int* __restrict__ start1,
                                               const int* __restrict__ deg1,
                                               const float* __restrict__ rs1,
                                               const _Float16* __restrict__ hW,
                                               const float* __restrict__ b2,
                                               float* __restrict__ out) {
    int wid = threadIdx.x >> 6, lane = threadIdx.x & 63;
    int dst = blockIdx.x * 4 + wid;
    if (dst >= N_NODES) return;
    int half_id = lane >> 5, fl = lane & 31;   // lane owns features 2*fl, 2*fl+1
    const int* deg1in = deg1 + 3 * N_NODES;
    const half2v* h2 = (const half2v*)hW;
    float2 a0 = make_float2(0.f, 0.f), a1 = a0, a2 = a0;
    accum_rel2(sorted1, start1[dst], deg1in[dst], h2, lane, half_id, fl, a0);
    accum_rel2(sorted1 + N_EDGES, start1[N_NODES + dst], deg1in[N_NODES + dst],
               h2 + 32, lane, half_id, fl, a1);
    accum_rel2(sorted1 + 2 * N_EDGES, start1[2 * N_NODES + dst], deg1in[2 * N_NODES + dst],
               h2 + 64, lane, half_id, fl, a2);
    // merge edge-parity halves
    a0.x += __shfl_xor(a0.x, 32); a0.y += __shfl_xor(a0.y, 32);
    a1.x += __shfl_xor(a1.x, 32); a1.y += __shfl_xor(a1.y, 32);
    a2.x += __shfl_xor(a2.x, 32); a2.y += __shfl_xor(a2.y, 32);
    if (!half_id) {
        float w0 = rs1[3 * N_NODES + dst], w1 = rs1[4 * N_NODES + dst],
              w2 = rs1[5 * N_NODES + dst];
        int f = 2 * fl;
        float ox = a0.x * w0 + a1.x * w1 + a2.x * w2 + b2[f] + b2[64 + f] + b2[128 + f];
        float oy = a0.y * w0 + a1.y * w1 + a2.y * w2 +
                   b2[f + 1] + b2[64 + f + 1] + b2[128 + f + 1];
        ((float2*)out)[(size_t)dst * 32 + fl] = make_float2(ox, oy);
    }
}

extern "C" void kernel_launch(void* const* d_in, const int* in_sizes, int n_in,
                              void* d_out, int out_size, void* d_ws, size_t ws_size,
                              hipStream_t stream) {
    (void)in_sizes; (void)n_in; (void)out_size; (void)ws_size;
    const float* x  = (const float*)d_in[0];
    const float* W1 = (const float*)d_in[1];
    const float* b1 = (const float*)d_in[2];
    const float* W2 = (const float*)d_in[3];
    const float* b2 = (const float*)d_in[4];
    const int*   ei = (const int*)d_in[5];
    float* out = (float*)d_out;

    char* ws = (char*)d_ws;
    int*      deg     = (int*)(ws + OFF_DEG);
    int*      gcount  = (int*)(ws + OFF_GC);
    int*      bbase   = (int*)(ws + OFF_BB);
    int*      bcursor = (int*)(ws + OFF_BC);
    float*    rs      = (float*)(ws + OFF_RS);
    int*      start   = (int*)(ws + OFF_START);
    int*      pairs   = (int*)(ws + OFF_PAIRS);
    _Float16* xh      = (_Float16*)(ws + OFF_XH);
    _Float16* W1f     = (_Float16*)(ws + OFF_W1F);
    _Float16* W2f     = (_Float16*)(ws + OFF_W2F);
    _Float16* agg     = (_Float16*)(ws + OFF_AGG);
    _Float16* hW      = (_Float16*)(ws + OFF_HW);
    short*    dds     = (short*)(ws + OFF_DDS);
    int*      gcount_s= (int*)(ws + OFF_GCS);
    int*      bbase_s = (int*)(ws + OFF_BBS);
    int*      bcursor_s=(int*)(ws + OFF_BCS);

    hipMemsetAsync(gcount, 0, 6144, stream);
    hipMemsetAsync(gcount_s, 0, 6144, stream);

    k_cvt_x<<<25000, 256, 0, stream>>>(x, xh);
    k_repack<<<288, 256, 0, stream>>>(W1, W2, W1f, W2f);
    k_bhist2<<<dim3(NCHUNK, 6), 256, 0, stream>>>(ei, gcount, gcount_s);
    k_bscan<<<6, 256, 0, stream>>>(gcount, bbase, bcursor);
    k_bscan<<<6, 256, 0, stream>>>(gcount_s, bbase_s, bcursor_s);
    k_bpart<<<dim3(NCHUNK, 6), 256, 0, stream>>>(ei, bcursor, pairs);
    k_bpart_s<<<dim3(NCHUNK, 6), 256, 0, stream>>>(ei, bcursor_s, dds);
    k_bsort<<<dim3(NBUCK, 6), 256, 0, stream>>>(bbase, pairs, start, deg);
    k_bcount_s<<<dim3(NBUCK, 6), 256, 0, stream>>>(bbase_s, dds, deg);
    k_rsqrt<<<4688, 256, 0, stream>>>(deg, rs);
    k_pull1<<<25000, 256, 0, stream>>>(pairs, start, deg, rs, xh, agg);
    k_gemm12<<<(MTILES + 3) / 4, 256, 0, stream>>>(agg, W1f, b1, W2f,
                                                   rs + 6 * (size_t)N_NODES, hW);
    k_pull2<<<25000, 256, 0, stream>>>(pairs + 3 * (size_t)N_EDGES,
                                       start + 3 * (size_t)N_NODES,
                                       deg + 6 * (size_t)N_NODES,
                                       rs + 6 * (size_t)N_NODES,
                                       hW, b2, out);
}